// Round 11
// baseline (24592.062 us; speedup 1.0000x reference)
//
#include <hip/hip_runtime.h>
#include <hip/hip_bf16.h>

using bf16 = __hip_bfloat16;
using short8 = __attribute__((ext_vector_type(8))) short;
using f32x4 = __attribute__((ext_vector_type(4))) float;

#define BB 512
#define HH 1024
#define DD 64
#define TT 96

__device__ __forceinline__ float sigm(float x) { return 1.0f / (1.0f + __expf(-x)); }
__device__ __forceinline__ float tanh_f(float x) {
  float e = __expf(2.0f * x);
  return 1.0f - 2.0f / (e + 1.0f);
}
__device__ __forceinline__ float wred(float v) {
#pragma unroll
  for (int m = 1; m < 64; m <<= 1) v += __shfl_xor(v, m, 64);
  return v;
}

// gate-row permutation: col c (= g*1024 + n) -> pr = (n>>4)*64 + g*16 + (n&15)
// => every 64-col group is [i16|f16|g16|o16] for 16 consecutive units.
__device__ __forceinline__ int gate_perm(int c) {
  int g = c >> 10, n = c & 1023;
  return (n >> 4) * 64 + g * 16 + (n & 15);
}

// ---------------- preprocessing kernels ----------------

__global__ __launch_bounds__(256) void init_states_k(
    const float* __restrict__ x0, const float* __restrict__ hn, const float* __restrict__ cn,
    bf16* __restrict__ xbh, bf16* __restrict__ xbl,
    bf16* __restrict__ h0h, bf16* __restrict__ h0l,
    bf16* __restrict__ h1h, bf16* __restrict__ h1l,
    float* __restrict__ c0, float* __restrict__ c1)
{
  int i = blockIdx.x * 256 + threadIdx.x;
  if (i < BB * HH) {
    float v0 = hn[i];
    bf16 a0 = __float2bfloat16(v0);
    h0h[i] = a0; h0l[i] = __float2bfloat16(v0 - __bfloat162float(a0));
    float v1 = hn[BB * HH + i];
    bf16 a1 = __float2bfloat16(v1);
    h1h[i] = a1; h1l[i] = __float2bfloat16(v1 - __bfloat162float(a1));
    c0[i] = cn[i];
    c1[i] = cn[BB * HH + i];
  }
  if (i < BB * DD) {
    float v = x0[i];
    bf16 a = __float2bfloat16(v);
    xbh[i] = a; xbl[i] = __float2bfloat16(v - __bfloat162float(a));
  }
}

__global__ __launch_bounds__(256) void fold_emb_k(
    const float* __restrict__ embW, const float* __restrict__ embB,
    const float* __restrict__ Wih0, const float* __restrict__ bih0, const float* __restrict__ bhh0,
    bf16* __restrict__ W0h, bf16* __restrict__ W0l, float* __restrict__ bias0)
{
  __shared__ float sW[512 * 8];
  __shared__ float sb[512];
  int tid = threadIdx.x;
  int d0 = blockIdx.y * 8;
  for (int i = tid; i < 4096; i += 256) {
    int j = i >> 9, e = i & 511;
    sW[e * 8 + j] = embW[(size_t)(d0 + j) * 512 + e];
  }
  for (int i = tid; i < 512; i += 256) sb[i] = embB[i];
  __syncthreads();
  int c = blockIdx.x * 256 + tid;
  float acc[8] = {0, 0, 0, 0, 0, 0, 0, 0};
  float bacc = 0.0f;
  for (int e = 0; e < 512; ++e) {
    float wv = Wih0[(size_t)e * 4096 + c];
    float4 wa = *(const float4*)&sW[e * 8];
    float4 wb = *(const float4*)&sW[e * 8 + 4];
    acc[0] += wa.x * wv; acc[1] += wa.y * wv; acc[2] += wa.z * wv; acc[3] += wa.w * wv;
    acc[4] += wb.x * wv; acc[5] += wb.y * wv; acc[6] += wb.z * wv; acc[7] += wb.w * wv;
    bacc += sb[e] * wv;
  }
  int pr = gate_perm(c);
#pragma unroll
  for (int j = 0; j < 8; ++j) {
    float v = acc[j];
    bf16 h = __float2bfloat16(v);
    W0h[(size_t)pr * 1088 + d0 + j] = h;
    W0l[(size_t)pr * 1088 + d0 + j] = __float2bfloat16(v - __bfloat162float(h));
  }
  if (blockIdx.y == 0) bias0[pr] = bacc + bih0[c] + bhh0[c];
}

template <bool PERM>
__global__ __launch_bounds__(256) void transpose_conv_k(
    const float* __restrict__ src, int N,
    bf16* __restrict__ dsth, bf16* __restrict__ dstl, int dstStride, int k0)
{
  __shared__ float tb[32][33];
  int tx = threadIdx.x & 31;
  int ty = threadIdx.x >> 5;
  int c0 = blockIdx.x * 32;
  int kk0 = blockIdx.y * 32;
#pragma unroll
  for (int q = 0; q < 4; ++q) {
    int k = kk0 + q * 8 + ty;
    tb[q * 8 + ty][tx] = src[(size_t)k * N + c0 + tx];
  }
  __syncthreads();
#pragma unroll
  for (int q = 0; q < 4; ++q) {
    int cc = c0 + q * 8 + ty;
    int pr = PERM ? gate_perm(cc) : cc;
    float v = tb[tx][q * 8 + ty];
    bf16 h = __float2bfloat16(v);
    size_t di = (size_t)pr * dstStride + k0 + kk0 + tx;
    dsth[di] = h;
    dstl[di] = __float2bfloat16(v - __bfloat162float(h));
  }
}

__global__ __launch_bounds__(256) void bias_perm_k(
    const float* __restrict__ a, const float* __restrict__ b, float* __restrict__ out)
{
  int c = blockIdx.x * 256 + threadIdx.x;
  out[gate_perm(c)] = a[c] + b[c];
}

// ---------------- gates GEMM + LSTM cell ----------------
// 512 blocks x 256 thr (2 blocks/CU, 8 waves/CU). Wave tile 16m x 64n.
// All operands direct global->VGPR; 3-deep register pipeline; no barriers,
// no LDS. XCD affinity: panel % 8 == bid % 8.
struct GF { short8 ah, al, bh[4], bl[4]; };

__global__ __launch_bounds__(256, 2) void gates_k(
    const bf16* __restrict__ A1h, const bf16* __restrict__ A1l, int lda1, int K1len,
    const bf16* __restrict__ A2h, const bf16* __restrict__ A2l, int lda2,
    const bf16* __restrict__ Bh, const bf16* __restrict__ Bl, int KTOT, int nt,
    const float* __restrict__ bias,
    float* __restrict__ cst, bf16* __restrict__ hho, bf16* __restrict__ hlo)
{
  const int tid = threadIdx.x, bid = blockIdx.x;
  const int lane = tid & 63, wv = tid >> 6;
  const int x = bid & 7, pq = (bid >> 3) & 3, mg = bid >> 5;
  const int panel = x + 8 * pq;            // 0..31, XCD = panel%8 = bid%8
  const int m0 = mg * 32 + (wv & 1) * 16;
  const int wn = wv >> 1;
  const int l15 = lane & 15, lhi = lane >> 4;

  const bf16* pBh[4];
  const bf16* pBl[4];
#pragma unroll
  for (int nf = 0; nf < 4; ++nf) {
    size_t ro = (size_t)(panel * 128 + wn * 64 + nf * 16 + l15) * KTOT + lhi * 8;
    pBh[nf] = Bh + ro;
    pBl[nf] = Bl + ro;
  }

  f32x4 acc[4];
#pragma unroll
  for (int i = 0; i < 4; ++i) acc[i] = f32x4{0, 0, 0, 0};

  auto ldt = [&](int t, GF& f) {
    int kt = t << 5;
    const bf16 *sh, *sl; int ko, ld;
    if (kt < K1len) { sh = A1h; sl = A1l; ko = kt; ld = lda1; }
    else            { sh = A2h; sl = A2l; ko = kt - K1len; ld = lda2; }
    size_t o = (size_t)(m0 + l15) * ld + ko + lhi * 8;
    f.ah = *(const short8*)(sh + o);
    f.al = *(const short8*)(sl + o);
#pragma unroll
    for (int nf = 0; nf < 4; ++nf) {
      f.bh[nf] = *(const short8*)(pBh[nf] + kt);
      f.bl[nf] = *(const short8*)(pBl[nf] + kt);
    }
  };

  auto cmp = [&](GF& f) {
#pragma unroll
    for (int nf = 0; nf < 4; ++nf) {
      f32x4 c = acc[nf];
      c = __builtin_amdgcn_mfma_f32_16x16x32_bf16(f.ah, f.bh[nf], c, 0, 0, 0);
      c = __builtin_amdgcn_mfma_f32_16x16x32_bf16(f.ah, f.bl[nf], c, 0, 0, 0);
      c = __builtin_amdgcn_mfma_f32_16x16x32_bf16(f.al, f.bh[nf], c, 0, 0, 0);
      acc[nf] = c;
    }
  };

  GF fa, fb, fc;
  ldt(0, fa); ldt(1, fb); ldt(2, fc);
  for (int t = 0; t < nt; t += 3) {
    cmp(fa);
    if (t + 3 < nt) ldt(t + 3, fa);
    if (t + 1 < nt) {
      cmp(fb);
      if (t + 4 < nt) ldt(t + 4, fb);
    }
    if (t + 2 < nt) {
      cmp(fc);
      if (t + 5 < nt) ldt(t + 5, fc);
    }
  }

  const int unit = panel * 32 + wn * 16 + l15;
  const int prb = panel * 128 + wn * 64 + l15;
  float bi = bias[prb + 0];
  float bfv = bias[prb + 16];
  float bg = bias[prb + 32];
  float bo = bias[prb + 48];
  f32x4 ai = acc[0], af = acc[1], ag = acc[2], ao = acc[3];
#pragma unroll
  for (int r = 0; r < 4; ++r) {
    int row = m0 + lhi * 4 + r;
    size_t idx = (size_t)row * HH + unit;
    float iv = ai[r] + bi, fv = af[r] + bfv, gv = ag[r] + bg, ov = ao[r] + bo;
    float co = cst[idx];
    float cn2 = sigm(fv) * co + sigm(iv) * tanh_f(gv);
    cst[idx] = cn2;
    float hv = sigm(ov) * tanh_f(cn2);
    bf16 hh = __float2bfloat16(hv);
    hho[idx] = hh;
    hlo[idx] = __float2bfloat16(hv - __bfloat162float(hh));
  }
}

// ---------------- fc1 ----------------
// 256 blocks x 256 thr. Wave tile 16m x 32n; XCD-affine n-chunks.
__global__ __launch_bounds__(256, 2) void fc1_k(
    const bf16* __restrict__ Ah, const bf16* __restrict__ Al,
    const bf16* __restrict__ Bh, const bf16* __restrict__ Bl,
    const float* __restrict__ bias, float* __restrict__ z)
{
  const int tid = threadIdx.x, bid = blockIdx.x;
  const int lane = tid & 63, wv = tid >> 6;
  const int x = bid & 7, mg = bid >> 3;    // mg 0..31
  const int nchunk = x + 8 * wv;           // 0..31, XCD-affine
  const int m0 = mg * 16, n0 = nchunk * 32;
  const int l15 = lane & 15, lhi = lane >> 4;
  const int nt = 32;

  const bf16* pBh[2];
  const bf16* pBl[2];
#pragma unroll
  for (int nf = 0; nf < 2; ++nf) {
    size_t ro = (size_t)(n0 + nf * 16 + l15) * HH + lhi * 8;
    pBh[nf] = Bh + ro;
    pBl[nf] = Bl + ro;
  }

  f32x4 acc[2];
  acc[0] = f32x4{0, 0, 0, 0};
  acc[1] = f32x4{0, 0, 0, 0};

  struct FF { short8 ah, al, bh[2], bl[2]; };

  auto ldt = [&](int t, FF& f) {
    int kt = t << 5;
    size_t o = (size_t)(m0 + l15) * HH + kt + lhi * 8;
    f.ah = *(const short8*)(Ah + o);
    f.al = *(const short8*)(Al + o);
#pragma unroll
    for (int nf = 0; nf < 2; ++nf) {
      f.bh[nf] = *(const short8*)(pBh[nf] + kt);
      f.bl[nf] = *(const short8*)(pBl[nf] + kt);
    }
  };

  auto cmp = [&](FF& f) {
#pragma unroll
    for (int nf = 0; nf < 2; ++nf) {
      f32x4 c = acc[nf];
      c = __builtin_amdgcn_mfma_f32_16x16x32_bf16(f.ah, f.bh[nf], c, 0, 0, 0);
      c = __builtin_amdgcn_mfma_f32_16x16x32_bf16(f.ah, f.bl[nf], c, 0, 0, 0);
      c = __builtin_amdgcn_mfma_f32_16x16x32_bf16(f.al, f.bh[nf], c, 0, 0, 0);
      acc[nf] = c;
    }
  };

  FF fa, fb, fc;
  ldt(0, fa); ldt(1, fb); ldt(2, fc);
  for (int t = 0; t < nt; t += 3) {
    cmp(fa);
    if (t + 3 < nt) ldt(t + 3, fa);
    if (t + 1 < nt) {
      cmp(fb);
      if (t + 4 < nt) ldt(t + 4, fb);
    }
    if (t + 2 < nt) {
      cmp(fc);
      if (t + 5 < nt) ldt(t + 5, fc);
    }
  }

#pragma unroll
  for (int nf = 0; nf < 2; ++nf) {
    int col = n0 + nf * 16 + l15;
    float bb = bias[col];
#pragma unroll
    for (int r = 0; r < 4; ++r) {
      int row = m0 + lhi * 4 + r;
      z[(size_t)row * HH + col] = acc[nf][r] + bb;
    }
  }
}

// ---------------- LayerNorm + ReLU + fc2 + output + feedback ----------------
__global__ __launch_bounds__(256) void ln_fc2_k(
    const float* __restrict__ z, const float* __restrict__ lng, const float* __restrict__ lnb,
    const float* __restrict__ W2 /*[1024][64]*/, const float* __restrict__ b2,
    float* __restrict__ out /*[512][96][64]*/,
    bf16* __restrict__ xbh, bf16* __restrict__ xbl, int tstep)
{
  __shared__ float sa[4][1024];
  __shared__ float red[4][4][64];
  int tid = threadIdx.x, lane = tid & 63, w = tid >> 6;
  int row = blockIdx.x * 4 + w;
  float zv[16];
#pragma unroll
  for (int j = 0; j < 16; ++j) zv[j] = z[(size_t)row * 1024 + j * 64 + lane];
  float s = 0;
#pragma unroll
  for (int j = 0; j < 16; ++j) s += zv[j];
  s = wred(s);
  float mu = s * (1.0f / 1024.0f);
  float vs = 0;
#pragma unroll
  for (int j = 0; j < 16; ++j) { float d = zv[j] - mu; vs += d * d; }
  vs = wred(vs);
  float rstd = rsqrtf(vs * (1.0f / 1024.0f) + 1e-5f);
#pragma unroll
  for (int j = 0; j < 16; ++j) {
    int k = j * 64 + lane;
    float a = (zv[j] - mu) * rstd * lng[k] + lnb[k];
    sa[w][k] = a > 0.0f ? a : 0.0f;
  }
  __syncthreads();
  int n = tid & 63, ks = (tid >> 6) * 256;
  float p0 = 0, p1 = 0, p2 = 0, p3 = 0;
  for (int k = ks; k < ks + 256; ++k) {
    float wv2 = W2[(size_t)k * 64 + n];
    p0 += sa[0][k] * wv2; p1 += sa[1][k] * wv2; p2 += sa[2][k] * wv2; p3 += sa[3][k] * wv2;
  }
  int sl = tid >> 6;
  red[0][sl][n] = p0; red[1][sl][n] = p1; red[2][sl][n] = p2; red[3][sl][n] = p3;
  __syncthreads();
  int rr = tid >> 6;
  float y = red[rr][0][n] + red[rr][1][n] + red[rr][2][n] + red[rr][3][n] + b2[n];
  int orow = blockIdx.x * 4 + rr;
  out[((size_t)orow * TT + tstep) * DD + n] = y;
  bf16 hh = __float2bfloat16(y);
  xbh[(size_t)orow * DD + n] = hh;
  xbl[(size_t)orow * DD + n] = __float2bfloat16(y - __bfloat162float(hh));
}

// ---------------- host ----------------

extern "C" void kernel_launch(void* const* d_in, const int* in_sizes, int n_in,
                              void* d_out, int out_size, void* d_ws, size_t ws_size,
                              hipStream_t stream)
{
  const float* x0   = (const float*)d_in[0];
  const float* hn   = (const float*)d_in[1];
  const float* cn   = (const float*)d_in[2];
  const float* embW = (const float*)d_in[4];
  const float* embB = (const float*)d_in[5];
  const float* Wih0 = (const float*)d_in[6];
  const float* Whh0 = (const float*)d_in[7];
  const float* bih0 = (const float*)d_in[8];
  const float* bhh0 = (const float*)d_in[9];
  const float* Wih1 = (const float*)d_in[10];
  const float* Whh1 = (const float*)d_in[11];
  const float* bih1 = (const float*)d_in[12];
  const float* bhh1 = (const float*)d_in[13];
  const float* fc1W = (const float*)d_in[14];
  const float* fc1b = (const float*)d_in[15];
  const float* lng  = (const float*)d_in[16];
  const float* lnb  = (const float*)d_in[17];
  const float* fc2W = (const float*)d_in[18];
  const float* fc2b = (const float*)d_in[19];

  char* wp = (char*)d_ws;
  size_t off = 0;
  auto alloc = [&](size_t bytes) -> void* {
    void* p = wp + off;
    off += (bytes + 255) & ~(size_t)255;
    return p;
  };

  bf16* W0th  = (bf16*)alloc((size_t)4096 * 1088 * 2);
  bf16* W0tl  = (bf16*)alloc((size_t)4096 * 1088 * 2);
  bf16* W1th  = (bf16*)alloc((size_t)4096 * 2048 * 2);
  bf16* W1tl  = (bf16*)alloc((size_t)4096 * 2048 * 2);
  bf16* f1h   = (bf16*)alloc((size_t)1024 * 1024 * 2);
  bf16* f1l   = (bf16*)alloc((size_t)1024 * 1024 * 2);
  float* bias0 = (float*)alloc(4096 * 4);
  float* bias1 = (float*)alloc(4096 * 4);
  bf16* xbh   = (bf16*)alloc((size_t)BB * DD * 2);
  bf16* xbl   = (bf16*)alloc((size_t)BB * DD * 2);
  bf16* h0h_a = (bf16*)alloc((size_t)BB * HH * 2);
  bf16* h0h_b = (bf16*)alloc((size_t)BB * HH * 2);
  bf16* h0l_a = (bf16*)alloc((size_t)BB * HH * 2);
  bf16* h0l_b = (bf16*)alloc((size_t)BB * HH * 2);
  bf16* h1h_a = (bf16*)alloc((size_t)BB * HH * 2);
  bf16* h1h_b = (bf16*)alloc((size_t)BB * HH * 2);
  bf16* h1l_a = (bf16*)alloc((size_t)BB * HH * 2);
  bf16* h1l_b = (bf16*)alloc((size_t)BB * HH * 2);
  float* c0   = (float*)alloc((size_t)BB * HH * 4);
  float* c1   = (float*)alloc((size_t)BB * HH * 4);
  float* z    = (float*)alloc((size_t)BB * HH * 4);

  init_states_k<<<2048, 256, 0, stream>>>(x0, hn, cn, xbh, xbl, h0h_a, h0l_a,
                                          h1h_a, h1l_a, c0, c1);
  fold_emb_k<<<dim3(16, 8), 256, 0, stream>>>(embW, embB, Wih0, bih0, bhh0, W0th, W0tl, bias0);
  transpose_conv_k<true><<<dim3(128, 32), 256, 0, stream>>>(Whh0, 4096, W0th, W0tl, 1088, 64);
  transpose_conv_k<true><<<dim3(128, 32), 256, 0, stream>>>(Wih1, 4096, W1th, W1tl, 2048, 0);
  transpose_conv_k<true><<<dim3(128, 32), 256, 0, stream>>>(Whh1, 4096, W1th, W1tl, 2048, 1024);
  transpose_conv_k<false><<<dim3(32, 32), 256, 0, stream>>>(fc1W, 1024, f1h, f1l, 1024, 0);
  bias_perm_k<<<16, 256, 0, stream>>>(bih1, bhh1, bias1);

  bf16* h0h[2] = {h0h_a, h0h_b};
  bf16* h0l[2] = {h0l_a, h0l_b};
  bf16* h1h[2] = {h1h_a, h1h_b};
  bf16* h1l[2] = {h1l_a, h1l_b};
  float* outp = (float*)d_out;

  for (int t = 0; t < TT; ++t) {
    int p = t & 1;
    // gates0 (+cell0): A = [x | h0_prev], K = 1088 (nt = 34)
    gates_k<<<512, 256, 0, stream>>>(
        xbh, xbl, DD, DD, h0h[p], h0l[p], HH, W0th, W0tl, 1088, 34, bias0,
        c0, h0h[p ^ 1], h0l[p ^ 1]);
    // gates1 (+cell1): A = [h0_cur | h1_prev], K = 2048 (nt = 64)
    gates_k<<<512, 256, 0, stream>>>(
        h0h[p ^ 1], h0l[p ^ 1], HH, HH, h1h[p], h1l[p], HH, W1th, W1tl, 2048, 64, bias1,
        c1, h1h[p ^ 1], h1l[p ^ 1]);
    // fc1: z = h1_cur @ fc1W + b (nt = 32)
    fc1_k<<<256, 256, 0, stream>>>(h1h[p ^ 1], h1l[p ^ 1], f1h, f1l, fc1b, z);
    // LN + ReLU + fc2 + write out[:, t, :] + feedback x hi/lo
    ln_fc2_k<<<128, 256, 0, stream>>>(z, lng, lnb, fc2W, fc2b, outp, xbh, xbl, t);
  }
}